// Round 1
// baseline (538.116 us; speedup 1.0000x reference)
//
#include <hip/hip_runtime.h>

typedef short s16x8 __attribute__((ext_vector_type(8)));
typedef float f32x4 __attribute__((ext_vector_type(4)));

#define DIM     512
#define BATCH   256
#define NTRI    131328          // (512*512+512)/2
#define FDIM    131840          // 512 + NTRI
#define KBLOCKS 2060            // FDIM / 64
#define BN      64
#define NTILES  8               // 512 / BN

__device__ __forceinline__ unsigned short f2bf(float f) {
  __bf16 h = (__bf16)f;                       // RNE hardware cvt
  return __builtin_bit_cast(unsigned short, h);
}
__device__ __forceinline__ float bf2f(unsigned short s) {
  union { unsigned u; float f; } v; v.u = (unsigned)s << 16; return v.f;
}

// ---------- setup: pair index table, p -> (i<<16|j), triu order ----------
__global__ void build_table(unsigned* __restrict__ table) {
  int i = blockIdx.x;                          // 0..511
  int base = i * DIM - (i * (i - 1)) / 2;
  int len = DIM - i;
  for (int t = threadIdx.x; t < len; t += blockDim.x)
    table[base + t] = ((unsigned)i << 16) | (unsigned)(i + t);
}

// ---------- setup: x[256][512] f32 -> Xt[512][256] bf16 ----------
__global__ void transpose_x(const float* __restrict__ x, unsigned short* __restrict__ Xt) {
  int t = blockIdx.x * blockDim.x + threadIdx.x;   // 131072
  int r = t & (BATCH - 1);
  int c = t >> 8;
  Xt[c * BATCH + r] = f2bf(x[r * DIM + c]);
}

// ---------- fused quad-feature GEMM: partial[chunk] += feat[256,Kc] @ W[n0:n0+64,:]^T ----------
__global__ __launch_bounds__(512, 4)
void qgemm(const unsigned* __restrict__ table,
           const unsigned short* __restrict__ Xt,   // [512][256] bf16
           const float* __restrict__ W,             // [512][131840] f32
           float* __restrict__ partial,             // [C][256][512]
           int C)
{
  __shared__ unsigned short As[BATCH * 64];         // 32 KB, XOR-swizzled slots
  const int ntile = blockIdx.x & (NTILES - 1);
  const int chunk = blockIdx.x >> 3;
  const int kb0 = (KBLOCKS * chunk) / C;
  const int kb1 = (KBLOCKS * (chunk + 1)) / C;
  const int n0 = ntile * BN;
  const int tid = threadIdx.x;
  const int lane = tid & 63;
  const int wave = tid >> 6;
  const int wm = wave & 3;                          // 4 waves along M (64 rows each)
  const int wn = wave >> 2;                         // 2 waves along N (32 cols each)
  const int lm = lane & 15;
  const int lk = lane >> 4;

  f32x4 acc[4][2] = {};

  const float* wbase = W + (size_t)(n0 + wn * 32 + lm) * FDIM + lk * 8;

  for (int kb = kb0; kb < kb1; ++kb) {
    // ---- stage feature tile [256 x 64] bf16 into LDS ----
    #pragma unroll
    for (int it = 0; it < 4; ++it) {
      int u = tid + it * 512;                       // 2048 units: (m, 8-wide k slot)
      int m = u & 255;
      int s8 = u >> 8;                              // 0..7
      int kg0 = kb * 64 + s8 * 8;
      unsigned short v[8];
      if (kg0 >= DIM) {                             // quadratic features
        int p0 = kg0 - DIM;
        #pragma unroll
        for (int e = 0; e < 8; ++e) {
          unsigned ij = table[p0 + e];              // wave-uniform
          float xi = bf2f(Xt[(ij >> 16) * BATCH + m]);
          float xj = bf2f(Xt[(ij & 0xffffu) * BATCH + m]);
          v[e] = f2bf(xi * xj);
        }
      } else {                                      // linear features (kb < 8)
        #pragma unroll
        for (int e = 0; e < 8; ++e)
          v[e] = Xt[(kg0 + e) * BATCH + m];
      }
      uint4 pk;
      pk.x = (unsigned)v[0] | ((unsigned)v[1] << 16);
      pk.y = (unsigned)v[2] | ((unsigned)v[3] << 16);
      pk.z = (unsigned)v[4] | ((unsigned)v[5] << 16);
      pk.w = (unsigned)v[6] | ((unsigned)v[7] << 16);
      int slot = s8 ^ (m & 7);                      // bank-conflict swizzle
      *(uint4*)((char*)As + m * 128 + slot * 16) = pk;
    }
    __syncthreads();

    // ---- compute: 2 k-steps of 32, 4x2 fragments per wave ----
    #pragma unroll
    for (int ks = 0; ks < 2; ++ks) {
      s16x8 bfr[2];
      #pragma unroll
      for (int nf = 0; nf < 2; ++nf) {
        const float* p = wbase + (size_t)nf * 16 * FDIM + kb * 64 + ks * 32;
        float4 w0 = *(const float4*)p;
        float4 w1 = *(const float4*)(p + 4);
        uint4 pk;
        pk.x = (unsigned)f2bf(w0.x) | ((unsigned)f2bf(w0.y) << 16);
        pk.y = (unsigned)f2bf(w0.z) | ((unsigned)f2bf(w0.w) << 16);
        pk.z = (unsigned)f2bf(w1.x) | ((unsigned)f2bf(w1.y) << 16);
        pk.w = (unsigned)f2bf(w1.z) | ((unsigned)f2bf(w1.w) << 16);
        bfr[nf] = __builtin_bit_cast(s16x8, pk);
      }
      s16x8 afr[4];
      #pragma unroll
      for (int mf = 0; mf < 4; ++mf) {
        int m = wm * 64 + mf * 16 + lm;
        int slot = (ks * 4 + lk) ^ (m & 7);
        afr[mf] = *(const s16x8*)((const char*)As + m * 128 + slot * 16);
      }
      #pragma unroll
      for (int mf = 0; mf < 4; ++mf)
        #pragma unroll
        for (int nf = 0; nf < 2; ++nf)
          acc[mf][nf] = __builtin_amdgcn_mfma_f32_16x16x32_bf16(afr[mf], bfr[nf], acc[mf][nf], 0, 0, 0);
    }
    __syncthreads();
  }

  // ---- write partial tile ----
  float* pout = partial + (size_t)chunk * (BATCH * DIM);
  #pragma unroll
  for (int mf = 0; mf < 4; ++mf) {
    #pragma unroll
    for (int nf = 0; nf < 2; ++nf) {
      int mrow = wm * 64 + mf * 16 + lk * 4;        // C/D: col=lane&15, row=(lane>>4)*4+reg
      int ncol = n0 + wn * 32 + nf * 16 + lm;
      #pragma unroll
      for (int r = 0; r < 4; ++r)
        pout[(size_t)(mrow + r) * DIM + ncol] = acc[mf][nf][r];
    }
  }
}

// ---------- reductions ----------
__global__ void reduce_h(const float* __restrict__ partial, const float* __restrict__ bias,
                         unsigned short* __restrict__ Ht, int C) {
  int t = blockIdx.x * blockDim.x + threadIdx.x;   // 131072
  int b = t >> 9;
  int o = t & (DIM - 1);
  float s = bias[o];
  #pragma unroll 4
  for (int c = 0; c < C; ++c) s += partial[(size_t)c * (BATCH * DIM) + t];
  Ht[o * BATCH + b] = f2bf(s);                     // transposed bf16 for layer-2 feature gen
}

__global__ void reduce_out(const float* __restrict__ partial, const float* __restrict__ bias,
                           float* __restrict__ out, int C) {
  int t = blockIdx.x * blockDim.x + threadIdx.x;   // 131072
  int o = t & (DIM - 1);
  float s = bias[o];
  #pragma unroll 4
  for (int c = 0; c < C; ++c) s += partial[(size_t)c * (BATCH * DIM) + t];
  out[t] = s;
}

extern "C" void kernel_launch(void* const* d_in, const int* in_sizes, int n_in,
                              void* d_out, int out_size, void* d_ws, size_t ws_size,
                              hipStream_t stream) {
  const float* x  = (const float*)d_in[0];
  const float* W0 = (const float*)d_in[1];
  const float* b0 = (const float*)d_in[2];
  const float* W1 = (const float*)d_in[3];
  const float* b1 = (const float*)d_in[4];
  float* out = (float*)d_out;

  char* ws = (char*)d_ws;
  unsigned* table    = (unsigned*)ws;                        // 525,312 B (= 513 KiB)
  unsigned short* Xt = (unsigned short*)(ws + 525312);       // 262,144 B
  unsigned short* Ht = (unsigned short*)(ws + 787456);       // 262,144 B
  float* partial     = (float*)(ws + 1049600);               // C * 512 KiB

  size_t avail = (ws_size > 1049600) ? (ws_size - 1049600) : 0;
  int C = (int)(avail / ((size_t)BATCH * DIM * sizeof(float)));
  if (C > 64) C = 64;
  if (C < 1)  C = 1;

  build_table<<<dim3(512), dim3(256), 0, stream>>>(table);
  transpose_x<<<dim3(512), dim3(256), 0, stream>>>(x, Xt);

  qgemm<<<dim3(NTILES * C), dim3(512), 0, stream>>>(table, Xt, W0, partial, C);
  reduce_h<<<dim3(512), dim3(256), 0, stream>>>(partial, b0, Ht, C);

  qgemm<<<dim3(NTILES * C), dim3(512), 0, stream>>>(table, Ht, W1, partial, C);
  reduce_out<<<dim3(512), dim3(256), 0, stream>>>(partial, b1, out, C);
}